// Round 5
// baseline (569.470 us; speedup 1.0000x reference)
//
#include <hip/hip_runtime.h>
#include <math.h>

#define SS 2048
#define QP 72   // bf16 pitch sQ (48 rows/head)
#define KP 72   // bf16 pitch sK (80 rows/head)
#define VP 72   // bf16 pitch sVt (64 d-rows/head, 64 key cols)
#define SP 84   // f32 pitch sS (48 rows/head, 80 cols)
#define PP 72   // bf16 pitch sP (32 rows/head, 64 cols)

typedef __attribute__((ext_vector_type(8))) short s8v;
typedef __attribute__((ext_vector_type(4))) float f4v;

__device__ __forceinline__ unsigned short f2b(float x) {
    union { float f; unsigned u; } v; v.f = x;
    unsigned r = v.u + 0x7FFFu + ((v.u >> 16) & 1u);
    return (unsigned short)(r >> 16);
}

__device__ __forceinline__ unsigned long long pack4(float4 v) {
    return (unsigned long long)f2b(v.x) | ((unsigned long long)f2b(v.y) << 16)
         | ((unsigned long long)f2b(v.z) << 32) | ((unsigned long long)f2b(v.w) << 48);
}

__global__ __launch_bounds__(1024, 4)
void mta_v5(const float* __restrict__ Q, const float* __restrict__ K,
            const float* __restrict__ V, const float* __restrict__ CW,
            const float* __restrict__ CB, const float* __restrict__ MIX,
            const float* __restrict__ GAM, const float* __restrict__ BET,
            float* __restrict__ OUT)
{
    __shared__ __align__(16) unsigned short sQ[2 * 48 * QP];  // 13824 B
    __shared__ __align__(16) unsigned short sK[2 * 80 * KP];  // 23040 B
    __shared__ __align__(16) unsigned short sVt[2 * 64 * VP]; // 18432 B
    __shared__ __align__(16) float sS[2 * 48 * SP];           // 32256 B (reused as sO, pitch 68)
    __shared__ __align__(16) unsigned short sP[2 * 32 * PP];  // 9216 B
    __shared__ float sResc[2][32];
    __shared__ float sL[2][32];
    __shared__ float sW[2][66];
    __shared__ float sB[2];
    // ~97.3 KB total -> exactly 1 block/CU on gfx950 (160 KB LDS)

    const int tid = threadIdx.x;
    const int g = blockIdx.x & 7;
    const int u = blockIdx.x >> 3;   // 0..31

    const int wv = tid >> 6, lane = tid & 63;
    const int lrow = lane & 15;            // MFMA A/B row, C col
    const int lk8 = (lane >> 4) << 3;      // MFMA k-offset
    const int crow4 = (lane >> 4) << 2;    // MFMA C row base

    // conv/softmax mapping: 2 heads x 32 rows x 16 key-quads
    const int ch = tid >> 9;
    const int cq = (tid >> 4) & 31;
    const int ck = tid & 15;

    // PV wave role: (i = source head, j = dest head, kh = key half, nh = n half)
    const int i_pv = wv >> 3, j_pv = (wv >> 2) & 1, kh = (wv >> 1) & 1, nh = wv & 1;

    for (int idx = tid; idx < 132; idx += 1024) {
        int h = idx / 66, w = idx - h * 66;
        sW[h][w] = CW[(2 * g + h) * 66 + w];
    }
    if (tid < 2) sB[tid] = CB[2 * g + tid];
    const float mixc = MIX[g * 4 + i_pv * 2 + j_pv];

    const float4* Q4 = (const float4*)Q;
    const float4* K4 = (const float4*)K;
    const float4* V4 = (const float4*)V;

    for (int ti = 0; ti < 2; ++ti) {
        const int tile = ti ? u : (63 - u);   // per-block iteration total is constant (33)
        const int q0 = tile << 5;
        __syncthreads(); // protects sQ restage and sO(sS) reuse vs previous ti readers

        // ---- stage extended Q tile (rows q0-2 .. q0+45), bf16 ----
        for (int idx = tid; idx < 1536; idx += 1024) {
            int h = idx / 768, rem = idx - h * 768;
            int e = rem >> 4, d4 = rem & 15;
            int r = q0 - 2 + e;
            float4 val = make_float4(0.f, 0.f, 0.f, 0.f);
            if (r >= 0 && r < SS) val = Q4[((2 * g + h) * SS + r) * 16 + d4];
            *(unsigned long long*)&sQ[(h * 48 + e) * QP + (d4 << 2)] = pack4(val);
        }

        f4v acc[2][2];
#pragma unroll
        for (int mt = 0; mt < 2; ++mt)
#pragma unroll
            for (int n2 = 0; n2 < 2; ++n2) acc[mt][n2] = f4v{0.f, 0.f, 0.f, 0.f};
        float m_run = -INFINITY, l_run = 0.f;

        const int iters = (tile >> 1) + 1;   // 64 keys per iteration
        for (int it = 0; it < iters; ++it) {
            const int k0 = it << 6;
            __syncthreads(); // B1: prev PV done w/ sVt,sP,sResc; prev scores done w/ sK; Q staged

            // ---- stage extended K (cols k0-5 .. k0+68 -> slots 0..73; 74..79 zero) ----
            for (int idx = tid; idx < 2560; idx += 1024) {
                int h = idx / 1280, rem = idx - h * 1280;
                int e = rem >> 4, d4 = rem & 15;
                int c = k0 - 5 + e;
                float4 val = make_float4(0.f, 0.f, 0.f, 0.f);
                if (e < 74 && c >= 0 && c < SS) val = K4[((2 * g + h) * SS + c) * 16 + d4];
                *(unsigned long long*)&sK[(h * 80 + e) * KP + (d4 << 2)] = pack4(val);
            }
            // ---- stage V transposed: sVt[h][d][k], 64 keys ----
            for (int idx = tid; idx < 2048; idx += 1024) {
                int h = idx >> 10, d4 = (idx >> 6) & 15, kk = idx & 63;
                float4 val = V4[((2 * g + h) * SS + k0 + kk) * 16 + d4];
                int d = d4 << 2;
                sVt[(h * 64 + d + 0) * VP + kk] = f2b(val.x);
                sVt[(h * 64 + d + 1) * VP + kk] = f2b(val.y);
                sVt[(h * 64 + d + 2) * VP + kk] = f2b(val.z);
                sVt[(h * 64 + d + 3) * VP + kk] = f2b(val.w);
            }
            __syncthreads(); // B2

            // ---- scores: 2 heads x 3 m-tiles x 5 n-tiles, K=64 ----
            for (int job = wv; job < 30; job += 16) {
                int h = job / 15, r15 = job - h * 15;
                int mt = r15 / 5, nt = r15 - mt * 5;
                const unsigned short* ap = &sQ[(h * 48 + mt * 16 + lrow) * QP + lk8];
                const unsigned short* bp = &sK[(h * 80 + nt * 16 + lrow) * KP + lk8];
                f4v c = f4v{0.f, 0.f, 0.f, 0.f};
                c = __builtin_amdgcn_mfma_f32_16x16x32_bf16(*(const s8v*)ap,
                                                            *(const s8v*)bp, c, 0, 0, 0);
                c = __builtin_amdgcn_mfma_f32_16x16x32_bf16(*(const s8v*)(ap + 32),
                                                            *(const s8v*)(bp + 32), c, 0, 0, 0);
                int col = nt * 16 + lrow;
                int cab = k0 - 5 + col;
                int rbase = mt * 16 + crow4;
#pragma unroll
                for (int r = 0; r < 4; ++r)
                    sS[(h * 48 + rbase + r) * SP + col] = (cab <= q0 - 2 + rbase + r) ? c[r] * 0.125f : 0.f;
            }
            __syncthreads(); // B3

            // ---- conv (4 keys/thread) + causal re-mask + online softmax ----
            {
                const int c0 = ck << 2;
                float a4[4];
                float bias = sB[ch];
#pragma unroll
                for (int kk = 0; kk < 4; ++kk) a4[kk] = bias;
#pragma unroll
                for (int i = 0; i < 6; ++i) {
                    const float* base = &sS[(ch * 48 + cq + i) * SP + c0];
                    float4 x0 = *(const float4*)&base[0];
                    float4 x1 = *(const float4*)&base[4];
                    float4 x2 = *(const float4*)&base[8];
                    float4 x3 = *(const float4*)&base[12];
                    float s[16] = {x0.x, x0.y, x0.z, x0.w, x1.x, x1.y, x1.z, x1.w,
                                   x2.x, x2.y, x2.z, x2.w, x3.x, x3.y, x3.z, x3.w};
                    float wr[11];
#pragma unroll
                    for (int jj = 0; jj < 11; ++jj) wr[jj] = sW[ch][i * 11 + jj];
#pragma unroll
                    for (int kk = 0; kk < 4; ++kk)
#pragma unroll
                        for (int jj = 0; jj < 11; ++jj)
                            a4[kk] = fmaf(wr[jj], s[kk + jj], a4[kk]);
                }
                const int r_abs = q0 + cq;
                float tmax = -INFINITY;
#pragma unroll
                for (int kk = 0; kk < 4; ++kk) {
                    int cab = k0 + c0 + kk;
                    if (cab > r_abs) a4[kk] = -1e9f;
                    tmax = fmaxf(tmax, a4[kk]);
                }
                tmax = fmaxf(tmax, __shfl_xor(tmax, 1));
                tmax = fmaxf(tmax, __shfl_xor(tmax, 2));
                tmax = fmaxf(tmax, __shfl_xor(tmax, 4));
                tmax = fmaxf(tmax, __shfl_xor(tmax, 8));
                float mnew = fmaxf(m_run, tmax);
                float resc = __expf(m_run - mnew); // first iter: exp(-inf)=0
                float p0 = __expf(a4[0] - mnew), p1 = __expf(a4[1] - mnew);
                float p2 = __expf(a4[2] - mnew), p3 = __expf(a4[3] - mnew);
                float psum = (p0 + p1) + (p2 + p3);
                psum += __shfl_xor(psum, 1);
                psum += __shfl_xor(psum, 2);
                psum += __shfl_xor(psum, 4);
                psum += __shfl_xor(psum, 8);
                l_run = l_run * resc + psum;
                m_run = mnew;
                if (ck == 0) sResc[ch][cq] = resc;
                *(unsigned long long*)&sP[(ch * 32 + cq) * PP + c0] =
                    pack4(make_float4(p0, p1, p2, p3));
            }
            __syncthreads(); // B4

            // ---- PV: wave (i,j,kh,nh): acc += P_i[kh-half] @ V_j[nh-half tiles] ----
            {
#pragma unroll
                for (int mt = 0; mt < 2; ++mt)
#pragma unroll
                    for (int r = 0; r < 4; ++r) {
                        float f = sResc[i_pv][mt * 16 + crow4 + r];
                        acc[mt][0][r] *= f;
                        acc[mt][1][r] *= f;
                    }
#pragma unroll
                for (int mt = 0; mt < 2; ++mt) {
                    s8v a = *(const s8v*)&sP[(i_pv * 32 + mt * 16 + lrow) * PP + (kh << 5) + lk8];
#pragma unroll
                    for (int n2 = 0; n2 < 2; ++n2) {
                        s8v b = *(const s8v*)&sVt[(j_pv * 64 + (nh * 2 + n2) * 16 + lrow) * VP + (kh << 5) + lk8];
                        acc[mt][n2] = __builtin_amdgcn_mfma_f32_16x16x32_bf16(a, b, acc[mt][n2], 0, 0, 0);
                    }
                }
            }
        } // it

        if (ck == 0) sL[ch][cq] = l_run;
        __syncthreads(); // B5

        // ---- head mixing: 4 barriered stages over (i_pv, kh) into sO ----
        float* sO = sS;
#pragma unroll
        for (int st = 0; st < 4; ++st) {
            if (i_pv == (st >> 1) && kh == (st & 1)) {
#pragma unroll
                for (int mt = 0; mt < 2; ++mt)
#pragma unroll
                    for (int r = 0; r < 4; ++r) {
                        int row = mt * 16 + crow4 + r;
                        float cc = mixc / sL[i_pv][row];
#pragma unroll
                        for (int n2 = 0; n2 < 2; ++n2) {
                            int col = (nh * 2 + n2) * 16 + lrow;
                            float val = acc[mt][n2][r] * cc;
                            if (st == 0) sO[(j_pv * 32 + row) * 68 + col] = val;
                            else         sO[(j_pv * 32 + row) * 68 + col] += val;
                        }
                    }
            }
            __syncthreads();
        }

        // ---- LayerNorm over D + store (one item per thread) ----
        {
            const float4* G4 = (const float4*)GAM;
            const float4* B4 = (const float4*)BET;
            int d4 = tid & 15, rowj = tid >> 4; // 0..63
            int j = rowj >> 5, qq = rowj & 31;
            float4 o = *(const float4*)&sO[rowj * 68 + (d4 << 2)];
            float s1 = o.x + o.y + o.z + o.w;
            float s2 = o.x * o.x + o.y * o.y + o.z * o.z + o.w * o.w;
#pragma unroll
            for (int off = 1; off < 16; off <<= 1) {
                s1 += __shfl_xor(s1, off);
                s2 += __shfl_xor(s2, off);
            }
            float mean = s1 * (1.f / 64.f);
            float var = s2 * (1.f / 64.f) - mean * mean;
            float rs = rsqrtf(var + 1e-5f);
            float4 gm = G4[d4], bt = B4[d4];
            float4 ov;
            ov.x = (o.x - mean) * rs * gm.x + bt.x;
            ov.y = (o.y - mean) * rs * gm.y + bt.y;
            ov.z = (o.z - mean) * rs * gm.z + bt.z;
            ov.w = (o.w - mean) * rs * gm.w + bt.w;
            *(float4*)&OUT[(((2 * g + j) * SS + q0 + qq) << 6) + (d4 << 2)] = ov;
        }
    } // ti
}

extern "C" void kernel_launch(void* const* d_in, const int* in_sizes, int n_in,
                              void* d_out, int out_size, void* d_ws, size_t ws_size,
                              hipStream_t stream) {
    const float* q = (const float*)d_in[0];
    const float* k = (const float*)d_in[1];
    const float* v = (const float*)d_in[2];
    const float* cw = (const float*)d_in[3];
    const float* cb = (const float*)d_in[4];
    const float* mix = (const float*)d_in[5];
    const float* gam = (const float*)d_in[6];
    const float* bet = (const float*)d_in[7];
    float* out = (float*)d_out;

    dim3 grid(8 * 32);   // 256 blocks; ~97 KB LDS guarantees 1 block/CU
    dim3 block(1024);    // 16 waves = 4 waves/SIMD
    hipLaunchKernelGGL(mta_v5, grid, block, 0, stream,
                       q, k, v, cw, cb, mix, gam, bet, out);
}

// Round 6
// 272.032 us; speedup vs baseline: 2.0934x; 2.0934x over previous
//
#include <hip/hip_runtime.h>
#include <math.h>

#define SS 2048
#define QP 72   // bf16 pitch sQ (48 rows/head)
#define KP 72   // bf16 pitch sK (80 rows/head)
#define VP 72   // bf16 pitch sVt (64 d-rows/head, 64 key cols)
#define SP 84   // f32 pitch sS (48 rows/head, 80 cols)
#define PP 72   // bf16 pitch sP (32 rows/head, 64 cols)

typedef __attribute__((ext_vector_type(8))) short s8v;
typedef __attribute__((ext_vector_type(4))) float f4v;

__device__ __forceinline__ unsigned short f2b(float x) {
    union { float f; unsigned u; } v; v.f = x;
    unsigned r = v.u + 0x7FFFu + ((v.u >> 16) & 1u);
    return (unsigned short)(r >> 16);
}

__device__ __forceinline__ unsigned long long pack4(float4 v) {
    return (unsigned long long)f2b(v.x) | ((unsigned long long)f2b(v.y) << 16)
         | ((unsigned long long)f2b(v.z) << 32) | ((unsigned long long)f2b(v.w) << 48);
}

__global__ __launch_bounds__(512, 2)
void mta_v6(const float* __restrict__ Q, const float* __restrict__ K,
            const float* __restrict__ V, const float* __restrict__ CW,
            const float* __restrict__ CB, const float* __restrict__ MIX,
            const float* __restrict__ GAM, const float* __restrict__ BET,
            float* __restrict__ OUT)
{
    __shared__ __align__(16) unsigned short sQ[2 * 48 * QP];  // 13824 B
    __shared__ __align__(16) unsigned short sK[2 * 80 * KP];  // 23040 B
    __shared__ __align__(16) unsigned short sVt[2 * 64 * VP]; // 18432 B
    __shared__ __align__(16) float sS[2 * 48 * SP];           // 32256 B (reused as sO, pitch 68)
    __shared__ __align__(16) unsigned short sP[2 * 32 * PP];  // 9216 B
    __shared__ float sResc[2][32];
    __shared__ float sL[2][32];
    __shared__ float sW[2][66];
    __shared__ float sB[2];
    // ~97.3 KB -> hardware-guaranteed 1 block/CU (2x97 KB > 160 KB)

    const int tid = threadIdx.x;
    const int g = blockIdx.x & 7;
    const int u = blockIdx.x >> 3;   // 0..31

    const int wv = tid >> 6, lane = tid & 63;
    const int lrow = lane & 15;            // MFMA A/B row, C col
    const int lk8 = (lane >> 4) << 3;      // MFMA k-offset
    const int crow4 = (lane >> 4) << 2;    // MFMA C row base

    // conv/softmax mapping: 2 heads x 32 rows x 8 key-octs
    const int ch = tid >> 8;
    const int cq = (tid >> 3) & 31;
    const int ck = tid & 7;

    // PV wave role: (i = source head, j = dest head, kh = key half)
    const int i_pv = wv >> 2, j_pv = (wv >> 1) & 1, kh = wv & 1;

    for (int idx = tid; idx < 132; idx += 512) {
        int h = idx / 66, w = idx - h * 66;
        sW[h][w] = CW[(2 * g + h) * 66 + w];
    }
    if (tid < 2) sB[tid] = CB[2 * g + tid];
    const float mixc = MIX[g * 4 + i_pv * 2 + j_pv];

    const float4* Q4 = (const float4*)Q;
    const float4* K4 = (const float4*)K;
    const float4* V4 = (const float4*)V;

    for (int ti = 0; ti < 2; ++ti) {
        const int tile = ti ? u : (63 - u);   // per-block iteration total constant (33)
        const int q0 = tile << 5;
        __syncthreads(); // prev epilogue readers done with sO(sS)

        // ---- stage extended Q tile (rows q0-2 .. q0+45), bf16 ----
        for (int idx = tid; idx < 1536; idx += 512) {
            int h = idx / 768, rem = idx - h * 768;
            int e = rem >> 4, d4 = rem & 15;
            int r = q0 - 2 + e;
            float4 val = make_float4(0.f, 0.f, 0.f, 0.f);
            if (r >= 0 && r < SS) val = Q4[((2 * g + h) * SS + r) * 16 + d4];
            *(unsigned long long*)&sQ[(h * 48 + e) * QP + (d4 << 2)] = pack4(val);
        }

        f4v acc[2][4];
#pragma unroll
        for (int mt = 0; mt < 2; ++mt)
#pragma unroll
            for (int nt = 0; nt < 4; ++nt) acc[mt][nt] = f4v{0.f, 0.f, 0.f, 0.f};
        float m_run = -INFINITY, l_run = 0.f;

        const int iters = (tile >> 1) + 1;   // 64 keys per iteration
        for (int it = 0; it < iters; ++it) {
            const int k0 = it << 6;
            __syncthreads(); // B1: prev PV done w/ sVt,sP,sResc; prev scores done w/ sK; Q staged

            // ---- stage extended K (cols k0-5 .. k0+68 -> slots 0..73; 74..79 zero) ----
            for (int idx = tid; idx < 2560; idx += 512) {
                int h = idx / 1280, rem = idx - h * 1280;
                int e = rem >> 4, d4 = rem & 15;
                int c = k0 - 5 + e;
                float4 val = make_float4(0.f, 0.f, 0.f, 0.f);
                if (e < 74 && c >= 0 && c < SS) val = K4[((2 * g + h) * SS + c) * 16 + d4];
                *(unsigned long long*)&sK[(h * 80 + e) * KP + (d4 << 2)] = pack4(val);
            }
            // ---- stage V transposed: sVt[h][d][k], 64 keys ----
            for (int idx = tid; idx < 2048; idx += 512) {
                int h = idx >> 10, d4 = (idx >> 6) & 15, kk = idx & 63;
                float4 val = V4[((2 * g + h) * SS + k0 + kk) * 16 + d4];
                int d = d4 << 2;
                sVt[(h * 64 + d + 0) * VP + kk] = f2b(val.x);
                sVt[(h * 64 + d + 1) * VP + kk] = f2b(val.y);
                sVt[(h * 64 + d + 2) * VP + kk] = f2b(val.z);
                sVt[(h * 64 + d + 3) * VP + kk] = f2b(val.w);
            }
            __syncthreads(); // B2

            // ---- scores: 2 heads x 3 m-tiles x 5 n-tiles, K=64 ----
            for (int job = wv; job < 30; job += 8) {
                int h = job / 15, r15 = job - h * 15;
                int mt = r15 / 5, nt = r15 - mt * 5;
                const unsigned short* ap = &sQ[(h * 48 + mt * 16 + lrow) * QP + lk8];
                const unsigned short* bp = &sK[(h * 80 + nt * 16 + lrow) * KP + lk8];
                f4v c = f4v{0.f, 0.f, 0.f, 0.f};
                c = __builtin_amdgcn_mfma_f32_16x16x32_bf16(*(const s8v*)ap,
                                                            *(const s8v*)bp, c, 0, 0, 0);
                c = __builtin_amdgcn_mfma_f32_16x16x32_bf16(*(const s8v*)(ap + 32),
                                                            *(const s8v*)(bp + 32), c, 0, 0, 0);
                int col = nt * 16 + lrow;
                int cab = k0 - 5 + col;
                int rbase = mt * 16 + crow4;
#pragma unroll
                for (int r = 0; r < 4; ++r)
                    sS[(h * 48 + rbase + r) * SP + col] = (cab <= q0 - 2 + rbase + r) ? c[r] * 0.125f : 0.f;
            }
            __syncthreads(); // B3

            // ---- conv (8 keys/thread) + causal re-mask + online softmax ----
            {
                const int c0 = ck << 3;
                float a8[8];
                float bias = sB[ch];
#pragma unroll
                for (int kk = 0; kk < 8; ++kk) a8[kk] = bias;
#pragma unroll
                for (int i = 0; i < 6; ++i) {
                    const float* base = &sS[(ch * 48 + cq + i) * SP + c0];
                    float4 x0 = *(const float4*)&base[0];
                    float4 x1 = *(const float4*)&base[4];
                    float4 x2 = *(const float4*)&base[8];
                    float4 x3 = *(const float4*)&base[12];
                    float4 x4 = *(const float4*)&base[16];
                    float s[20] = {x0.x, x0.y, x0.z, x0.w, x1.x, x1.y, x1.z, x1.w,
                                   x2.x, x2.y, x2.z, x2.w, x3.x, x3.y, x3.z, x3.w,
                                   x4.x, x4.y, x4.z, x4.w};
                    float wr[11];
#pragma unroll
                    for (int jj = 0; jj < 11; ++jj) wr[jj] = sW[ch][i * 11 + jj];
#pragma unroll
                    for (int kk = 0; kk < 8; ++kk)
#pragma unroll
                        for (int jj = 0; jj < 11; ++jj)
                            a8[kk] = fmaf(wr[jj], s[kk + jj], a8[kk]);
                }
                const int r_abs = q0 + cq;
                float tmax = -INFINITY;
#pragma unroll
                for (int kk = 0; kk < 8; ++kk) {
                    int cab = k0 + c0 + kk;
                    if (cab > r_abs) a8[kk] = -1e9f;
                    tmax = fmaxf(tmax, a8[kk]);
                }
                tmax = fmaxf(tmax, __shfl_xor(tmax, 1));
                tmax = fmaxf(tmax, __shfl_xor(tmax, 2));
                tmax = fmaxf(tmax, __shfl_xor(tmax, 4));
                float mnew = fmaxf(m_run, tmax);
                float resc = __expf(m_run - mnew); // first iter: exp(-inf)=0
                float p[8];
                float psum = 0.f;
#pragma unroll
                for (int kk = 0; kk < 8; ++kk) {
                    p[kk] = __expf(a8[kk] - mnew);
                    psum += p[kk];
                }
                psum += __shfl_xor(psum, 1);
                psum += __shfl_xor(psum, 2);
                psum += __shfl_xor(psum, 4);
                l_run = l_run * resc + psum;
                m_run = mnew;
                if (ck == 0) sResc[ch][cq] = resc;
                s8v pv;
#pragma unroll
                for (int kk = 0; kk < 8; ++kk) pv[kk] = (short)f2b(p[kk]);
                *(s8v*)&sP[(ch * 32 + cq) * PP + c0] = pv;
            }
            __syncthreads(); // B4

            // ---- PV: wave (i,j,kh): acc += P_i[kh half] @ V_j ----
            {
#pragma unroll
                for (int mt = 0; mt < 2; ++mt)
#pragma unroll
                    for (int r = 0; r < 4; ++r) {
                        float f = sResc[i_pv][mt * 16 + crow4 + r];
#pragma unroll
                        for (int nt = 0; nt < 4; ++nt) acc[mt][nt][r] *= f;
                    }
#pragma unroll
                for (int mt = 0; mt < 2; ++mt) {
                    s8v a = *(const s8v*)&sP[(i_pv * 32 + mt * 16 + lrow) * PP + (kh << 5) + lk8];
#pragma unroll
                    for (int nt = 0; nt < 4; ++nt) {
                        s8v b = *(const s8v*)&sVt[(j_pv * 64 + nt * 16 + lrow) * VP + (kh << 5) + lk8];
                        acc[mt][nt] = __builtin_amdgcn_mfma_f32_16x16x32_bf16(a, b, acc[mt][nt], 0, 0, 0);
                    }
                }
            }
        } // it

        if (ck == 0) sL[ch][cq] = l_run;
        __syncthreads(); // B5

        // ---- head mixing: 4 barriered stages over (i_pv, kh) into sO ----
        float* sO = sS;
#pragma unroll
        for (int st = 0; st < 4; ++st) {
            if (i_pv == (st >> 1) && kh == (st & 1)) {
#pragma unroll
                for (int mt = 0; mt < 2; ++mt)
#pragma unroll
                    for (int r = 0; r < 4; ++r) {
                        int row = mt * 16 + crow4 + r;
                        float cc = mixc / sL[i_pv][row];
#pragma unroll
                        for (int nt = 0; nt < 4; ++nt) {
                            int col = nt * 16 + lrow;
                            float val = acc[mt][nt][r] * cc;
                            if (st == 0) sO[(j_pv * 32 + row) * 68 + col] = val;
                            else         sO[(j_pv * 32 + row) * 68 + col] += val;
                        }
                    }
            }
            __syncthreads();
        }

        // ---- LayerNorm over D + store (2 items/thread) ----
        {
            const float4* G4 = (const float4*)GAM;
            const float4* B4 = (const float4*)BET;
#pragma unroll
            for (int itl = 0; itl < 2; ++itl) {
                int pidx = tid + (itl << 9);
                int d4 = pidx & 15, rowj = pidx >> 4; // 0..63
                int j = rowj >> 5, qq = rowj & 31;
                float4 o = *(const float4*)&sO[rowj * 68 + (d4 << 2)];
                float s1 = o.x + o.y + o.z + o.w;
                float s2 = o.x * o.x + o.y * o.y + o.z * o.z + o.w * o.w;
#pragma unroll
                for (int off = 1; off < 16; off <<= 1) {
                    s1 += __shfl_xor(s1, off);
                    s2 += __shfl_xor(s2, off);
                }
                float mean = s1 * (1.f / 64.f);
                float var = s2 * (1.f / 64.f) - mean * mean;
                float rs = rsqrtf(var + 1e-5f);
                float4 gm = G4[d4], bt = B4[d4];
                float4 ov;
                ov.x = (o.x - mean) * rs * gm.x + bt.x;
                ov.y = (o.y - mean) * rs * gm.y + bt.y;
                ov.z = (o.z - mean) * rs * gm.z + bt.z;
                ov.w = (o.w - mean) * rs * gm.w + bt.w;
                *(float4*)&OUT[(((2 * g + j) * SS + q0 + qq) << 6) + (d4 << 2)] = ov;
            }
        }
    } // ti
}

extern "C" void kernel_launch(void* const* d_in, const int* in_sizes, int n_in,
                              void* d_out, int out_size, void* d_ws, size_t ws_size,
                              hipStream_t stream) {
    const float* q = (const float*)d_in[0];
    const float* k = (const float*)d_in[1];
    const float* v = (const float*)d_in[2];
    const float* cw = (const float*)d_in[3];
    const float* cb = (const float*)d_in[4];
    const float* mix = (const float*)d_in[5];
    const float* gam = (const float*)d_in[6];
    const float* bet = (const float*)d_in[7];
    float* out = (float*)d_out;

    dim3 grid(8 * 32);   // 256 blocks; ~97 KB LDS guarantees 1 block/CU
    dim3 block(512);     // 8 waves = 2 waves/SIMD, VGPR budget 256
    hipLaunchKernelGGL(mta_v6, grid, block, 0, stream,
                       q, k, v, cw, cb, mix, gam, bet, out);
}